// Round 1
// baseline (1254.909 us; speedup 1.0000x reference)
//
#include <hip/hip_runtime.h>
#include <math.h>

constexpr int Bc = 32;
constexpr int Tc = 4096;
constexpr int Dc = 256;
constexpr int Hc = 128;
constexpr float kTempInv = 2.0f;       // 1 / TEMPERATURE
constexpr float kThr = 0.4f;           // IRRELEVANCE_THRESHOLD
constexpr float kLnEps = 1e-5f;
constexpr float kNormEps = 1e-12f;
constexpr float kInvSqrt2 = 0.70710678118654752440f;

// ---------------- K1: attention scores (wave per token) ----------------
__global__ __launch_bounds__(256) void k_scores(const float* __restrict__ x,
                                                const float* __restrict__ tq,
                                                float* __restrict__ scores) {
  const int wave = threadIdx.x >> 6;
  const int lane = threadIdx.x & 63;
  const int base = blockIdx.x * 32 + wave * 8;
  const float4 q4 = reinterpret_cast<const float4*>(tq)[lane];
  for (int i = 0; i < 8; ++i) {
    const int tok = base + i;  // global token = b*T + t
    const float4 xv = reinterpret_cast<const float4*>(x + (size_t)tok * Dc)[lane];
    float p = xv.x * q4.x + xv.y * q4.y + xv.z * q4.z + xv.w * q4.w;
    #pragma unroll
    for (int off = 32; off > 0; off >>= 1) p += __shfl_xor(p, off, 64);
    if (lane == 0) scores[tok] = p * kTempInv;
  }
}

// ---------------- K2: per-batch softmax stats ----------------
__global__ __launch_bounds__(1024) void k_smstats(const float* __restrict__ scores,
                                                  float2* __restrict__ stats) {
  const int b = blockIdx.x, tid = threadIdx.x;
  const float4 v = reinterpret_cast<const float4*>(scores + (size_t)b * Tc)[tid];
  __shared__ float red[16];
  float m = fmaxf(fmaxf(v.x, v.y), fmaxf(v.z, v.w));
  #pragma unroll
  for (int off = 32; off > 0; off >>= 1) m = fmaxf(m, __shfl_xor(m, off, 64));
  if ((tid & 63) == 0) red[tid >> 6] = m;
  __syncthreads();
  if (tid == 0) {
    float gm = red[0];
    for (int i = 1; i < 16; ++i) gm = fmaxf(gm, red[i]);
    red[0] = gm;
  }
  __syncthreads();
  const float gmax = red[0];
  float s = expf(v.x - gmax) + expf(v.y - gmax) + expf(v.z - gmax) + expf(v.w - gmax);
  #pragma unroll
  for (int off = 32; off > 0; off >>= 1) s += __shfl_xor(s, off, 64);
  __syncthreads();
  if ((tid & 63) == 0) red[tid >> 6] = s;
  __syncthreads();
  if (tid == 0) {
    float t = 0.0f;
    for (int i = 0; i < 16; ++i) t += red[i];
    stats[b] = make_float2(gmax, t);
  }
}

// ---------------- K3: weighted sum -> main_topic (atomic partials) ----------------
__global__ __launch_bounds__(256) void k_wsum(const float* __restrict__ x,
                                              const float* __restrict__ scores,
                                              const float2* __restrict__ stats,
                                              float* __restrict__ mt) {
  const int b = blockIdx.x >> 4;
  const int chunk = blockIdx.x & 15;  // 256 tokens each
  const int d = threadIdx.x;
  const float2 st = stats[b];
  const int t0 = chunk * 256;
  const float* xb = x + ((size_t)b * Tc + t0) * Dc + d;
  const float* sb = scores + (size_t)b * Tc + t0;
  float acc = 0.0f;
  for (int i = 0; i < 256; ++i) {
    const float w = expf(sb[i] - st.x);
    acc += w * xb[(size_t)i * Dc];
  }
  atomicAdd(&mt[b * Dc + d], acc * (1.0f / st.y));
}

// ---------------- K4: encode main_topic -> normalized t_enc ----------------
__global__ __launch_bounds__(256) void k_tenc(
    const float* __restrict__ mt, const float* __restrict__ W1,
    const float* __restrict__ b1, const float* __restrict__ lng,
    const float* __restrict__ lnb, const float* __restrict__ W2,
    const float* __restrict__ b2, float* __restrict__ tnorm) {
  const int b = blockIdx.x, j = threadIdx.x;
  __shared__ float v[Dc];
  __shared__ float g[Dc];
  __shared__ float red[4];
  v[j] = mt[b * Dc + j];
  __syncthreads();
  float h = b1[j];
  for (int k = 0; k < Dc; ++k) h += v[k] * W1[(size_t)k * Dc + j];
  float s = h;
  #pragma unroll
  for (int off = 32; off > 0; off >>= 1) s += __shfl_xor(s, off, 64);
  if ((j & 63) == 0) red[j >> 6] = s;
  __syncthreads();
  const float mu = (red[0] + red[1] + red[2] + red[3]) * (1.0f / Dc);
  __syncthreads();
  const float dev = h - mu;
  float q = dev * dev;
  #pragma unroll
  for (int off = 32; off > 0; off >>= 1) q += __shfl_xor(q, off, 64);
  if ((j & 63) == 0) red[j >> 6] = q;
  __syncthreads();
  const float var = (red[0] + red[1] + red[2] + red[3]) * (1.0f / Dc);
  float hn = dev / sqrtf(var + kLnEps) * lng[j] + lnb[j];
  hn = 0.5f * hn * (1.0f + erff(hn * kInvSqrt2));
  g[j] = hn;
  __syncthreads();
  float z = 0.0f;
  if (j < Hc) {
    z = b2[j];
    for (int k = 0; k < Dc; ++k) z += g[k] * W2[(size_t)k * Hc + j];
  }
  float q2 = z * z;
  #pragma unroll
  for (int off = 32; off > 0; off >>= 1) q2 += __shfl_xor(q2, off, 64);
  __syncthreads();
  if ((j & 63) == 0) red[j >> 6] = q2;
  __syncthreads();
  if (j < Hc) {
    const float nrm = sqrtf(red[0] + red[1] + red[2] + red[3]);
    tnorm[b * Hc + j] = z / fmaxf(nrm, kNormEps);
  }
}

// ---------------- K5: encode all tokens + relevance mask ----------------
// 32 tokens/block, 256 threads. GEMM1 thread-tile 8x4 (ty:4 x tx:64),
// LN+GELU in registers (rows wave-local), GEMM2 thread-tile 4x4 (ty2:8 x tx2:32).
__global__ __launch_bounds__(256) void k_encode_mask(
    const float* __restrict__ x, const float* __restrict__ W1,
    const float* __restrict__ b1, const float* __restrict__ lng,
    const float* __restrict__ lnb, const float* __restrict__ W2,
    const float* __restrict__ b2, const float* __restrict__ tnorm,
    unsigned char* __restrict__ irr) {
  constexpr int LDW = 260;  // +4 floats pad
  __shared__ __align__(16) float sh[32 * LDW];
  __shared__ __align__(16) float tn[Hc];
  const int tid = threadIdx.x;
  const size_t tok0 = (size_t)blockIdx.x * 32;
  const int b = (int)(tok0 >> 12);  // T = 4096

  #pragma unroll
  for (int i = 0; i < 8; ++i) {
    const int f = tid + (i << 8);
    const int row = f >> 6, c4 = f & 63;
    const float4 v = reinterpret_cast<const float4*>(x + (tok0 + row) * Dc)[c4];
    *reinterpret_cast<float4*>(&sh[row * LDW + c4 * 4]) = v;
  }
  if (tid < Hc) tn[tid] = tnorm[b * Hc + tid];
  __syncthreads();

  // ---- GEMM1 ----
  const int tx = tid & 63, ty = tid >> 6;
  float4 acc[8];
  {
    const float4 bias = reinterpret_cast<const float4*>(b1)[tx];
    #pragma unroll
    for (int m = 0; m < 8; ++m) acc[m] = bias;
  }
  for (int k = 0; k < Dc; k += 4) {
    const float4 w0 = reinterpret_cast<const float4*>(W1 + (size_t)(k + 0) * Dc)[tx];
    const float4 w1 = reinterpret_cast<const float4*>(W1 + (size_t)(k + 1) * Dc)[tx];
    const float4 w2 = reinterpret_cast<const float4*>(W1 + (size_t)(k + 2) * Dc)[tx];
    const float4 w3 = reinterpret_cast<const float4*>(W1 + (size_t)(k + 3) * Dc)[tx];
    #pragma unroll
    for (int m = 0; m < 8; ++m) {
      const float4 xv = *reinterpret_cast<const float4*>(&sh[(ty * 8 + m) * LDW + k]);
      acc[m].x += xv.x * w0.x + xv.y * w1.x + xv.z * w2.x + xv.w * w3.x;
      acc[m].y += xv.x * w0.y + xv.y * w1.y + xv.z * w2.y + xv.w * w3.y;
      acc[m].z += xv.x * w0.z + xv.y * w1.z + xv.z * w2.z + xv.w * w3.z;
      acc[m].w += xv.x * w0.w + xv.y * w1.w + xv.z * w2.w + xv.w * w3.w;
    }
  }
  // ---- LN + GELU (rows are wave-local: no barrier needed before rewrite) ----
  {
    const float4 g4 = reinterpret_cast<const float4*>(lng)[tx];
    const float4 bb = reinterpret_cast<const float4*>(lnb)[tx];
    #pragma unroll
    for (int m = 0; m < 8; ++m) {
      float s = acc[m].x + acc[m].y + acc[m].z + acc[m].w;
      #pragma unroll
      for (int off = 32; off > 0; off >>= 1) s += __shfl_xor(s, off, 64);
      const float mu = s * (1.0f / Dc);
      const float ax = acc[m].x - mu, ay = acc[m].y - mu;
      const float az = acc[m].z - mu, aw = acc[m].w - mu;
      float q = ax * ax + ay * ay + az * az + aw * aw;
      #pragma unroll
      for (int off = 32; off > 0; off >>= 1) q += __shfl_xor(q, off, 64);
      const float inv = 1.0f / sqrtf(q * (1.0f / Dc) + kLnEps);
      float hx = ax * inv * g4.x + bb.x;
      float hy = ay * inv * g4.y + bb.y;
      float hz = az * inv * g4.z + bb.z;
      float hw = aw * inv * g4.w + bb.w;
      hx = 0.5f * hx * (1.0f + erff(hx * kInvSqrt2));
      hy = 0.5f * hy * (1.0f + erff(hy * kInvSqrt2));
      hz = 0.5f * hz * (1.0f + erff(hz * kInvSqrt2));
      hw = 0.5f * hw * (1.0f + erff(hw * kInvSqrt2));
      *reinterpret_cast<float4*>(&sh[(ty * 8 + m) * LDW + tx * 4]) =
          make_float4(hx, hy, hz, hw);
    }
  }
  __syncthreads();

  // ---- GEMM2 + relevance ----
  const int tx2 = tid & 31, ty2 = tid >> 5;
  float4 a2[4];
  {
    const float4 bias2 = reinterpret_cast<const float4*>(b2)[tx2];
    #pragma unroll
    for (int r = 0; r < 4; ++r) a2[r] = bias2;
  }
  for (int k = 0; k < Dc; k += 4) {
    const float4 u0 = reinterpret_cast<const float4*>(W2 + (size_t)(k + 0) * Hc)[tx2];
    const float4 u1 = reinterpret_cast<const float4*>(W2 + (size_t)(k + 1) * Hc)[tx2];
    const float4 u2 = reinterpret_cast<const float4*>(W2 + (size_t)(k + 2) * Hc)[tx2];
    const float4 u3 = reinterpret_cast<const float4*>(W2 + (size_t)(k + 3) * Hc)[tx2];
    #pragma unroll
    for (int r = 0; r < 4; ++r) {
      const float4 gq = *reinterpret_cast<const float4*>(&sh[(ty2 * 4 + r) * LDW + k]);
      a2[r].x += gq.x * u0.x + gq.y * u1.x + gq.z * u2.x + gq.w * u3.x;
      a2[r].y += gq.x * u0.y + gq.y * u1.y + gq.z * u2.y + gq.w * u3.y;
      a2[r].z += gq.x * u0.z + gq.y * u1.z + gq.z * u2.z + gq.w * u3.z;
      a2[r].w += gq.x * u0.w + gq.y * u1.w + gq.z * u2.w + gq.w * u3.w;
    }
  }
  {
    const float4 t4 = *reinterpret_cast<const float4*>(&tn[tx2 * 4]);
    #pragma unroll
    for (int r = 0; r < 4; ++r) {
      float ss = a2[r].x * a2[r].x + a2[r].y * a2[r].y +
                 a2[r].z * a2[r].z + a2[r].w * a2[r].w;
      float sd = a2[r].x * t4.x + a2[r].y * t4.y + a2[r].z * t4.z + a2[r].w * t4.w;
      #pragma unroll
      for (int off = 16; off > 0; off >>= 1) {
        ss += __shfl_xor(ss, off, 64);
        sd += __shfl_xor(sd, off, 64);
      }
      if (tx2 == 0) {
        const float rel = sd / fmaxf(sqrtf(ss), kNormEps);
        irr[tok0 + ty2 * 4 + r] = (rel < kThr) ? (unsigned char)1 : (unsigned char)0;
      }
    }
  }
}

// ---------------- K6: packed-pair FFT -> masked filter -> IFFT ----------------
// Stockham radix-2, no bit reversal; flattened indexing: per stage,
// a = src[r], b = src[r+2048], dst[d0]=a+b, dst[d0+s]=(a-b)*w with
// d0 = r + (r & ~(s-1)), w = tw[r & ~(s-1)].
__device__ __forceinline__ void fft_stages(float2* bufA, float2* bufB,
                                           const float2* tw, int tid, float sign) {
  float2* src = bufA;
  float2* dst = bufB;
  int s = 1;
  for (int stage = 0; stage < 12; ++stage) {
    const int notm = ~(s - 1);
    #pragma unroll
    for (int i = 0; i < 8; ++i) {
      const int r = tid + (i << 8);
      const float2 a = src[r];
      const float2 b = src[r + 2048];
      const float2 w = tw[r & notm];
      const float wy = w.y * sign;
      const float dr = a.x - b.x;
      const float di = a.y - b.y;
      const int d0 = r + (r & notm);
      dst[d0] = make_float2(a.x + b.x, a.y + b.y);
      dst[d0 + s] = make_float2(dr * w.x - di * wy, dr * wy + di * w.x);
    }
    __syncthreads();
    float2* t = src; src = dst; dst = t;
    s <<= 1;
  }
  // 12 stages (even) -> result back in bufA
}

__device__ __forceinline__ void mask_pair(float2* buf, const unsigned char* __restrict__ irb,
                                          int k, float ca, float sa, float cb, float sb) {
  const int m = (4096 - k) & 4095;
  const bool ik = irb[k] != 0;
  const bool im = irb[m] != 0;
  const float2 Zk = buf[k];
  const float2 Zm = buf[m];
  // true spectra of the two packed real channels at freq k
  const float Ar = 0.5f * (Zk.x + Zm.x), Ai = 0.5f * (Zk.y - Zm.y);
  const float Br = 0.5f * (Zk.y + Zm.y), Bi = -0.5f * (Zk.x - Zm.x);
  // G(k) = (g(k) + conj(g(N-k)))/2, g = irr ? e^{i phi} : 1
  const float Gar = 0.5f * ((ik ? ca : 1.0f) + (im ? ca : 1.0f));
  const float Gai = 0.5f * ((ik ? sa : 0.0f) - (im ? sa : 0.0f));
  const float Gbr = 0.5f * ((ik ? cb : 1.0f) + (im ? cb : 1.0f));
  const float Gbi = 0.5f * ((ik ? sb : 0.0f) - (im ? sb : 0.0f));
  // H = G * spectrum (Hermitian by construction after pairing)
  const float har = Gar * Ar - Gai * Ai, hai = Gar * Ai + Gai * Ar;
  const float hbr = Gbr * Br - Gbi * Bi, hbi = Gbr * Bi + Gbi * Br;
  buf[k] = make_float2(har - hbi, hai + hbr);        // H_a + i H_b
  buf[m] = make_float2(har + hbi, hbr - hai);        // conj(H_a) + i conj(H_b)
}

__global__ __launch_bounds__(256) void k_fft_filter(const float* __restrict__ x,
                                                    const unsigned char* __restrict__ irr,
                                                    const float* __restrict__ sf,
                                                    float* __restrict__ out) {
  __shared__ float2 bufA[4096];
  __shared__ float2 bufB[4096];
  __shared__ float2 tw[2048];
  const int b = blockIdx.x >> 7;   // 128 channel-pairs per batch
  const int pr = blockIdx.x & 127;
  const int c0 = pr * 2;
  const int tid = threadIdx.x;

  for (int i = tid; i < 2048; i += 256) {
    float sn, cn;
    sincosf(-1.5339807878856412e-3f * (float)i, &sn, &cn);  // -2*pi*i/4096
    tw[i] = make_float2(cn, sn);
  }
  const float* xb = x + ((size_t)b * Tc) * Dc + c0;
  #pragma unroll
  for (int i = 0; i < 16; ++i) {
    const int t = tid + (i << 8);
    bufA[t] = *reinterpret_cast<const float2*>(xb + (size_t)t * Dc);
  }
  __syncthreads();

  fft_stages(bufA, bufB, tw, tid, 1.0f);   // forward (ends in bufA)

  float sa, ca, sb, cb;
  sincosf(sf[c0 & 3], &sa, &ca);
  sincosf(sf[(c0 + 1) & 3], &sb, &cb);
  const unsigned char* irb = irr + (size_t)b * Tc;
  #pragma unroll
  for (int i = 0; i < 8; ++i) mask_pair(bufA, irb, tid + (i << 8), ca, sa, cb, sb);
  if (tid == 0) mask_pair(bufA, irb, 2048, ca, sa, cb, sb);
  __syncthreads();

  fft_stages(bufA, bufB, tw, tid, -1.0f);  // inverse (unscaled, ends in bufA)

  float* ob = out + ((size_t)b * Tc) * Dc + c0;
  constexpr float invN = 1.0f / 4096.0f;
  #pragma unroll
  for (int i = 0; i < 16; ++i) {
    const int t = tid + (i << 8);
    const float2 y = bufA[t];
    *reinterpret_cast<float2*>(ob + (size_t)t * Dc) = make_float2(y.x * invN, y.y * invN);
  }
}

// ---------------- launch ----------------
extern "C" void kernel_launch(void* const* d_in, const int* in_sizes, int n_in,
                              void* d_out, int out_size, void* d_ws, size_t ws_size,
                              hipStream_t stream) {
  const float* x   = (const float*)d_in[0];
  const float* W1  = (const float*)d_in[1];
  const float* b1  = (const float*)d_in[2];
  const float* lng = (const float*)d_in[3];
  const float* lnb = (const float*)d_in[4];
  const float* W2  = (const float*)d_in[5];
  const float* b2  = (const float*)d_in[6];
  const float* tq  = (const float*)d_in[7];
  const float* sf  = (const float*)d_in[8];
  float* out = (float*)d_out;

  char* ws = (char*)d_ws;
  float* scores       = (float*)(ws);                 // 32*4096*4      = 524288
  float* mt           = (float*)(ws + 524288);        // 32*256*4       = 32768
  float2* stats       = (float2*)(ws + 557056);       // 32*8           = 256
  float* tnorm        = (float*)(ws + 557312);        // 32*128*4       = 16384
  unsigned char* irr  = (unsigned char*)(ws + 573696);// 32*4096        = 131072

  hipMemsetAsync(mt, 0, Bc * Dc * sizeof(float), stream);

  k_scores<<<Bc * Tc / 32, 256, 0, stream>>>(x, tq, scores);
  k_smstats<<<Bc, 1024, 0, stream>>>(scores, stats);
  k_wsum<<<Bc * 16, 256, 0, stream>>>(x, scores, stats, mt);
  k_tenc<<<Bc, 256, 0, stream>>>(mt, W1, b1, lng, lnb, W2, b2, tnorm);
  k_encode_mask<<<Bc * Tc / 32, 256, 0, stream>>>(x, W1, b1, lng, lnb, W2, b2,
                                                  tnorm, irr);
  k_fft_filter<<<Bc * (Dc / 2), 256, 0, stream>>>(x, irr, sf, out);
}

// Round 3
// 779.526 us; speedup vs baseline: 1.6098x; 1.6098x over previous
//
#include <hip/hip_runtime.h>
#include <math.h>

typedef float f32x4 __attribute__((ext_vector_type(4)));
typedef __bf16 bh8 __attribute__((ext_vector_type(8)));

constexpr int Bc = 32;
constexpr int Tc = 4096;
constexpr int Dc = 256;
constexpr int Hc = 128;
constexpr float kTempInv = 2.0f;
constexpr float kThr = 0.4f;
constexpr float kLnEps = 1e-5f;
constexpr float kNormEps = 1e-12f;
constexpr float kInvSqrt2 = 0.70710678118654752440f;

__device__ __forceinline__ unsigned short f2bf(float f) {
  unsigned u = __float_as_uint(f);
  u += 0x7FFFu + ((u >> 16) & 1u);
  return (unsigned short)(u >> 16);
}
__device__ __forceinline__ float bf2f(unsigned short s) {
  return __uint_as_float(((unsigned)s) << 16);
}

// ---------------- K1: attention scores ----------------
__global__ __launch_bounds__(256) void k_scores(const float* __restrict__ x,
                                                const float* __restrict__ tq,
                                                float* __restrict__ scores) {
  const int wave = threadIdx.x >> 6;
  const int lane = threadIdx.x & 63;
  const int base = blockIdx.x * 32 + wave * 8;
  const float4 q4 = reinterpret_cast<const float4*>(tq)[lane];
  for (int i = 0; i < 8; ++i) {
    const int tok = base + i;
    const float4 xv = reinterpret_cast<const float4*>(x + (size_t)tok * Dc)[lane];
    float p = xv.x * q4.x + xv.y * q4.y + xv.z * q4.z + xv.w * q4.w;
    #pragma unroll
    for (int off = 32; off > 0; off >>= 1) p += __shfl_xor(p, off, 64);
    if (lane == 0) scores[tok] = p * kTempInv;
  }
}

// ---------------- K2: per-batch softmax stats ----------------
__global__ __launch_bounds__(1024) void k_smstats(const float* __restrict__ scores,
                                                  float2* __restrict__ stats) {
  const int b = blockIdx.x, tid = threadIdx.x;
  const float4 v = reinterpret_cast<const float4*>(scores + (size_t)b * Tc)[tid];
  __shared__ float red[16];
  float m = fmaxf(fmaxf(v.x, v.y), fmaxf(v.z, v.w));
  #pragma unroll
  for (int off = 32; off > 0; off >>= 1) m = fmaxf(m, __shfl_xor(m, off, 64));
  if ((tid & 63) == 0) red[tid >> 6] = m;
  __syncthreads();
  if (tid == 0) {
    float gm = red[0];
    for (int i = 1; i < 16; ++i) gm = fmaxf(gm, red[i]);
    red[0] = gm;
  }
  __syncthreads();
  const float gmax = red[0];
  float s = expf(v.x - gmax) + expf(v.y - gmax) + expf(v.z - gmax) + expf(v.w - gmax);
  #pragma unroll
  for (int off = 32; off > 0; off >>= 1) s += __shfl_xor(s, off, 64);
  __syncthreads();
  if ((tid & 63) == 0) red[tid >> 6] = s;
  __syncthreads();
  if (tid == 0) {
    float t = 0.0f;
    for (int i = 0; i < 16; ++i) t += red[i];
    stats[b] = make_float2(gmax, t);
  }
}

// ---------------- K3: weighted sum -> main_topic ----------------
__global__ __launch_bounds__(256) void k_wsum(const float* __restrict__ x,
                                              const float* __restrict__ scores,
                                              const float2* __restrict__ stats,
                                              float* __restrict__ mt) {
  const int b = blockIdx.x >> 4;
  const int chunk = blockIdx.x & 15;
  const int d = threadIdx.x;
  const float2 st = stats[b];
  const int t0 = chunk * 256;
  const float* xb = x + ((size_t)b * Tc + t0) * Dc + d;
  const float* sb = scores + (size_t)b * Tc + t0;
  float acc = 0.0f;
  for (int i = 0; i < 256; ++i) {
    const float w = expf(sb[i] - st.x);
    acc += w * xb[(size_t)i * Dc];
  }
  atomicAdd(&mt[b * Dc + d], acc * (1.0f / st.y));
}

// ---------------- K4: encode main_topic (exact fp32) ----------------
__global__ __launch_bounds__(256) void k_tenc(
    const float* __restrict__ mt, const float* __restrict__ W1,
    const float* __restrict__ b1, const float* __restrict__ lng,
    const float* __restrict__ lnb, const float* __restrict__ W2,
    const float* __restrict__ b2, float* __restrict__ tnorm) {
  const int b = blockIdx.x, j = threadIdx.x;
  __shared__ float v[Dc];
  __shared__ float g[Dc];
  __shared__ float red[4];
  v[j] = mt[b * Dc + j];
  __syncthreads();
  float h = b1[j];
  for (int k = 0; k < Dc; ++k) h += v[k] * W1[(size_t)k * Dc + j];
  float s = h;
  #pragma unroll
  for (int off = 32; off > 0; off >>= 1) s += __shfl_xor(s, off, 64);
  if ((j & 63) == 0) red[j >> 6] = s;
  __syncthreads();
  const float mu = (red[0] + red[1] + red[2] + red[3]) * (1.0f / Dc);
  __syncthreads();
  const float dev = h - mu;
  float q = dev * dev;
  #pragma unroll
  for (int off = 32; off > 0; off >>= 1) q += __shfl_xor(q, off, 64);
  if ((j & 63) == 0) red[j >> 6] = q;
  __syncthreads();
  const float var = (red[0] + red[1] + red[2] + red[3]) * (1.0f / Dc);
  float hn = dev / sqrtf(var + kLnEps) * lng[j] + lnb[j];
  hn = 0.5f * hn * (1.0f + erff(hn * kInvSqrt2));
  g[j] = hn;
  __syncthreads();
  float z = 0.0f;
  if (j < Hc) {
    z = b2[j];
    for (int k = 0; k < Dc; ++k) z += g[k] * W2[(size_t)k * Hc + j];
  }
  float q2 = z * z;
  #pragma unroll
  for (int off = 32; off > 0; off >>= 1) q2 += __shfl_xor(q2, off, 64);
  __syncthreads();
  if ((j & 63) == 0) red[j >> 6] = q2;
  __syncthreads();
  if (j < Hc) {
    const float nrm = sqrtf(red[0] + red[1] + red[2] + red[3]);
    tnorm[b * Hc + j] = z / fmaxf(nrm, kNormEps);
  }
}

// ---------------- K-prep: W1^T, W2^T split into bf16 hi/lo ----------------
// NOTE: runs AFTER k_wsum — its outputs overlay the (dead) scores region.
__global__ __launch_bounds__(256) void k_prep(const float* __restrict__ W1,
                                              const float* __restrict__ W2,
                                              unsigned short* __restrict__ w1h,
                                              unsigned short* __restrict__ w1l,
                                              unsigned short* __restrict__ w2h,
                                              unsigned short* __restrict__ w2l) {
  const int g = blockIdx.x * 256 + threadIdx.x;
  if (blockIdx.x < 64) {  // W1 [256 x 256] -> W1T[n][k]
    const int n = g >> 6;
    const int kq = (g & 63) * 4;
    unsigned h[2] = {0, 0}, l[2] = {0, 0};
    #pragma unroll
    for (int j = 0; j < 4; ++j) {
      const float v = W1[(size_t)(kq + j) * Dc + n];
      const unsigned short hb = f2bf(v);
      const unsigned short lb = f2bf(v - bf2f(hb));
      h[j >> 1] |= ((unsigned)hb) << ((j & 1) * 16);
      l[j >> 1] |= ((unsigned)lb) << ((j & 1) * 16);
    }
    *reinterpret_cast<uint2*>(&w1h[(size_t)n * Dc + kq]) = make_uint2(h[0], h[1]);
    *reinterpret_cast<uint2*>(&w1l[(size_t)n * Dc + kq]) = make_uint2(l[0], l[1]);
  } else {  // W2 [256 x 128] -> W2T[h][k]
    const int g2 = g - 16384;
    const int n = g2 >> 6;
    const int kq = (g2 & 63) * 4;
    unsigned h[2] = {0, 0}, l[2] = {0, 0};
    #pragma unroll
    for (int j = 0; j < 4; ++j) {
      const float v = W2[(size_t)(kq + j) * Hc + n];
      const unsigned short hb = f2bf(v);
      const unsigned short lb = f2bf(v - bf2f(hb));
      h[j >> 1] |= ((unsigned)hb) << ((j & 1) * 16);
      l[j >> 1] |= ((unsigned)lb) << ((j & 1) * 16);
    }
    *reinterpret_cast<uint2*>(&w2h[(size_t)n * Dc + kq]) = make_uint2(h[0], h[1]);
    *reinterpret_cast<uint2*>(&w2l[(size_t)n * Dc + kq]) = make_uint2(l[0], l[1]);
  }
}

// ---------------- K5: MFMA encode + relevance mask ----------------
// 64 tokens/block, 256 thr = 4 waves (2M x 2N). bf16x3 split-precision GEMMs.
// A-frag (16x16x32): M = lane&15, k = (lane>>4)*8 + j. B-frag: N = lane&15.
// C/D: col(N) = lane&15, row(M) = (lane>>4)*4 + reg.
__global__ __launch_bounds__(256, 2) void k_encode_mfma(
    const float* __restrict__ x,
    const unsigned short* __restrict__ w1h, const unsigned short* __restrict__ w1l,
    const unsigned short* __restrict__ w2h, const unsigned short* __restrict__ w2l,
    const float* __restrict__ b1, const float* __restrict__ lng,
    const float* __restrict__ lnb, const float* __restrict__ b2,
    const float* __restrict__ tnorm, unsigned char* __restrict__ irr) {
  constexpr int LDB = 264;   // bf16 elems per row (pad)
  constexpr int LDH = 260;   // fp32 elems per row (pad)
  __shared__ __align__(16) char uni[64 * LDB * 2 * 2];  // 67584 B union
  __shared__ float ps[2][64];
  __shared__ float psD[2][64];
  __shared__ float p_b1[Dc], p_g[Dc], p_bb[Dc], p_b2[Hc], p_tn[Hc];
  unsigned short* xh_hi = reinterpret_cast<unsigned short*>(uni);
  unsigned short* xh_lo = xh_hi + 64 * LDB;
  float* hbuf = reinterpret_cast<float*>(uni);

  const int tid = threadIdx.x;
  const size_t tok0 = (size_t)blockIdx.x * 64;
  const int b = (int)(tok0 >> 12);
  const int lane = tid & 63;
  const int wave = tid >> 6;
  const int wm = wave >> 1, wn = wave & 1;
  const int lrow = lane & 15, lkh = lane >> 4;

  p_b1[tid] = b1[tid];
  p_g[tid] = lng[tid];
  p_bb[tid] = lnb[tid];
  if (tid < Hc) {
    p_b2[tid] = b2[tid];
    p_tn[tid] = tnorm[b * Hc + tid];
  }
  // stage x tile as bf16 hi/lo
  #pragma unroll
  for (int i = 0; i < 16; ++i) {
    const int f = tid + (i << 8);
    const int row = f >> 6, c4 = f & 63;
    const float4 v = reinterpret_cast<const float4*>(x + (tok0 + row) * Dc)[c4];
    unsigned hp[2] = {0, 0}, lp[2] = {0, 0};
    const float vv[4] = {v.x, v.y, v.z, v.w};
    #pragma unroll
    for (int j = 0; j < 4; ++j) {
      const unsigned short hb = f2bf(vv[j]);
      const unsigned short lb = f2bf(vv[j] - bf2f(hb));
      hp[j >> 1] |= ((unsigned)hb) << ((j & 1) * 16);
      lp[j >> 1] |= ((unsigned)lb) << ((j & 1) * 16);
    }
    *reinterpret_cast<uint2*>(&xh_hi[row * LDB + c4 * 4]) = make_uint2(hp[0], hp[1]);
    *reinterpret_cast<uint2*>(&xh_lo[row * LDB + c4 * 4]) = make_uint2(lp[0], lp[1]);
  }
  __syncthreads();

  // ---- GEMM1: [64x256] @ [256x256], bf16x3 ----
  f32x4 acc1[2][8];
  #pragma unroll
  for (int mt = 0; mt < 2; ++mt)
    #pragma unroll
    for (int nt = 0; nt < 8; ++nt) acc1[mt][nt] = (f32x4){0.f, 0.f, 0.f, 0.f};

  for (int ks = 0; ks < 8; ++ks) {
    bh8 ah[2], al[2];
    #pragma unroll
    for (int mt = 0; mt < 2; ++mt) {
      const int off = (wm * 32 + mt * 16 + lrow) * LDB + ks * 32 + lkh * 8;
      ah[mt] = *reinterpret_cast<const bh8*>(&xh_hi[off]);
      al[mt] = *reinterpret_cast<const bh8*>(&xh_lo[off]);
    }
    #pragma unroll
    for (int nt = 0; nt < 8; ++nt) {
      const size_t boff = (size_t)(wn * 128 + nt * 16 + lrow) * Dc + ks * 32 + lkh * 8;
      const bh8 bh = *reinterpret_cast<const bh8*>(&w1h[boff]);
      const bh8 bl = *reinterpret_cast<const bh8*>(&w1l[boff]);
      #pragma unroll
      for (int mt = 0; mt < 2; ++mt) {
        acc1[mt][nt] = __builtin_amdgcn_mfma_f32_16x16x32_bf16(ah[mt], bh, acc1[mt][nt], 0, 0, 0);
        acc1[mt][nt] = __builtin_amdgcn_mfma_f32_16x16x32_bf16(al[mt], bh, acc1[mt][nt], 0, 0, 0);
        acc1[mt][nt] = __builtin_amdgcn_mfma_f32_16x16x32_bf16(ah[mt], bl, acc1[mt][nt], 0, 0, 0);
      }
    }
  }
  __syncthreads();  // all waves done reading xh (hbuf aliases it)

  // ---- bias + LN row stats (cross-wave via LDS partials) ----
  float s[2][4];
  #pragma unroll
  for (int mt = 0; mt < 2; ++mt)
    #pragma unroll
    for (int j = 0; j < 4; ++j) s[mt][j] = 0.0f;
  #pragma unroll
  for (int nt = 0; nt < 8; ++nt) {
    const int col = wn * 128 + nt * 16 + lrow;
    const float bv = p_b1[col];
    #pragma unroll
    for (int mt = 0; mt < 2; ++mt) {
      #pragma unroll
      for (int j = 0; j < 4; ++j) {
        acc1[mt][nt][j] += bv;
        s[mt][j] += acc1[mt][nt][j];
      }
    }
  }
  #pragma unroll
  for (int mt = 0; mt < 2; ++mt)
    #pragma unroll
    for (int j = 0; j < 4; ++j) {
      #pragma unroll
      for (int off = 8; off > 0; off >>= 1) s[mt][j] += __shfl_xor(s[mt][j], off, 64);
    }
  if (lrow == 0) {
    #pragma unroll
    for (int mt = 0; mt < 2; ++mt)
      #pragma unroll
      for (int j = 0; j < 4; ++j)
        ps[wn][wm * 32 + mt * 16 + lkh * 4 + j] = s[mt][j];
  }
  __syncthreads();
  float mu[2][4];
  #pragma unroll
  for (int mt = 0; mt < 2; ++mt)
    #pragma unroll
    for (int j = 0; j < 4; ++j) {
      const int r = wm * 32 + mt * 16 + lkh * 4 + j;
      mu[mt][j] = (ps[0][r] + ps[1][r]) * (1.0f / Dc);
    }
  float q[2][4];
  #pragma unroll
  for (int mt = 0; mt < 2; ++mt)
    #pragma unroll
    for (int j = 0; j < 4; ++j) q[mt][j] = 0.0f;
  #pragma unroll
  for (int nt = 0; nt < 8; ++nt)
    #pragma unroll
    for (int mt = 0; mt < 2; ++mt)
      #pragma unroll
      for (int j = 0; j < 4; ++j) {
        const float d = acc1[mt][nt][j] - mu[mt][j];
        q[mt][j] += d * d;
      }
  #pragma unroll
  for (int mt = 0; mt < 2; ++mt)
    #pragma unroll
    for (int j = 0; j < 4; ++j) {
      #pragma unroll
      for (int off = 8; off > 0; off >>= 1) q[mt][j] += __shfl_xor(q[mt][j], off, 64);
    }
  if (lrow == 0) {
    #pragma unroll
    for (int mt = 0; mt < 2; ++mt)
      #pragma unroll
      for (int j = 0; j < 4; ++j)
        psD[wn][wm * 32 + mt * 16 + lkh * 4 + j] = q[mt][j];
  }
  __syncthreads();
  float inv[2][4];
  #pragma unroll
  for (int mt = 0; mt < 2; ++mt)
    #pragma unroll
    for (int j = 0; j < 4; ++j) {
      const int r = wm * 32 + mt * 16 + lkh * 4 + j;
      const float var = (psD[0][r] + psD[1][r]) * (1.0f / Dc);
      inv[mt][j] = 1.0f / sqrtf(var + kLnEps);
    }
  // normalize + GELU -> hbuf fp32
  #pragma unroll
  for (int nt = 0; nt < 8; ++nt) {
    const int col = wn * 128 + nt * 16 + lrow;
    const float gv = p_g[col], bb = p_bb[col];
    #pragma unroll
    for (int mt = 0; mt < 2; ++mt)
      #pragma unroll
      for (int j = 0; j < 4; ++j) {
        float hv = (acc1[mt][nt][j] - mu[mt][j]) * inv[mt][j] * gv + bb;
        hv = 0.5f * hv * (1.0f + erff(hv * kInvSqrt2));
        hbuf[(wm * 32 + mt * 16 + lkh * 4 + j) * LDH + col] = hv;
      }
  }
  __syncthreads();

  // ---- GEMM2: [64x256] @ [256x128], bf16x3, A from hbuf ----
  f32x4 acc2[2][4];
  #pragma unroll
  for (int mt = 0; mt < 2; ++mt)
    #pragma unroll
    for (int nt = 0; nt < 4; ++nt) acc2[mt][nt] = (f32x4){0.f, 0.f, 0.f, 0.f};

  for (int ks = 0; ks < 8; ++ks) {
    bh8 ah[2], al[2];
    #pragma unroll
    for (int mt = 0; mt < 2; ++mt) {
      const int base = (wm * 32 + mt * 16 + lrow) * LDH + ks * 32 + lkh * 8;
      const f32x4 u0 = *reinterpret_cast<const f32x4*>(&hbuf[base]);
      const f32x4 u1 = *reinterpret_cast<const f32x4*>(&hbuf[base + 4]);
      union { unsigned short us[8]; bh8 v; } uh, ul;
      #pragma unroll
      for (int j = 0; j < 4; ++j) {
        const unsigned short hb = f2bf(u0[j]);
        uh.us[j] = hb;
        ul.us[j] = f2bf(u0[j] - bf2f(hb));
      }
      #pragma unroll
      for (int j = 0; j < 4; ++j) {
        const unsigned short hb = f2bf(u1[j]);
        uh.us[4 + j] = hb;
        ul.us[4 + j] = f2bf(u1[j] - bf2f(hb));
      }
      ah[mt] = uh.v;
      al[mt] = ul.v;
    }
    #pragma unroll
    for (int nt = 0; nt < 4; ++nt) {
      const size_t boff = (size_t)(wn * 64 + nt * 16 + lrow) * Dc + ks * 32 + lkh * 8;
      const bh8 bh = *reinterpret_cast<const bh8*>(&w2h[boff]);
      const bh8 bl = *reinterpret_cast<const bh8*>(&w2l[boff]);
      #pragma unroll
      for (int mt = 0; mt < 2; ++mt) {
        acc2[mt][nt] = __builtin_amdgcn_mfma_f32_16x16x32_bf16(ah[mt], bh, acc2[mt][nt], 0, 0, 0);
        acc2[mt][nt] = __builtin_amdgcn_mfma_f32_16x16x32_bf16(al[mt], bh, acc2[mt][nt], 0, 0, 0);
        acc2[mt][nt] = __builtin_amdgcn_mfma_f32_16x16x32_bf16(ah[mt], bl, acc2[mt][nt], 0, 0, 0);
      }
    }
  }

  // ---- cosine vs t_enc -> irr ----
  float ss[2][4], sd[2][4];
  #pragma unroll
  for (int mt = 0; mt < 2; ++mt)
    #pragma unroll
    for (int j = 0; j < 4; ++j) { ss[mt][j] = 0.0f; sd[mt][j] = 0.0f; }
  #pragma unroll
  for (int nt = 0; nt < 4; ++nt) {
    const int col2 = wn * 64 + nt * 16 + lrow;
    const float b2v = p_b2[col2], tv = p_tn[col2];
    #pragma unroll
    for (int mt = 0; mt < 2; ++mt)
      #pragma unroll
      for (int j = 0; j < 4; ++j) {
        const float z = acc2[mt][nt][j] + b2v;
        ss[mt][j] += z * z;
        sd[mt][j] += z * tv;
      }
  }
  #pragma unroll
  for (int mt = 0; mt < 2; ++mt)
    #pragma unroll
    for (int j = 0; j < 4; ++j) {
      #pragma unroll
      for (int off = 8; off > 0; off >>= 1) {
        ss[mt][j] += __shfl_xor(ss[mt][j], off, 64);
        sd[mt][j] += __shfl_xor(sd[mt][j], off, 64);
      }
    }
  if (lrow == 0) {
    #pragma unroll
    for (int mt = 0; mt < 2; ++mt)
      #pragma unroll
      for (int j = 0; j < 4; ++j) {
        const int r = wm * 32 + mt * 16 + lkh * 4 + j;
        ps[wn][r] = ss[mt][j];
        psD[wn][r] = sd[mt][j];
      }
  }
  __syncthreads();
  if (tid < 64) {
    const float S = ps[0][tid] + ps[1][tid];
    const float Dd = psD[0][tid] + psD[1][tid];
    const float rel = Dd / fmaxf(sqrtf(S), kNormEps);
    irr[tok0 + tid] = (rel < kThr) ? (unsigned char)1 : (unsigned char)0;
  }
}

// ---------------- generic 64x64 tiled transpose: in[b][r][c] -> out[b][c][r] ----------------
__global__ __launch_bounds__(256) void k_transpose(const float* __restrict__ in,
                                                   float* __restrict__ out,
                                                   int R, int C) {
  __shared__ float t[64][65];
  const int tilesC = C >> 6;
  const int perB = (R >> 6) * tilesC;
  const int bid = blockIdx.x;
  const int b = bid / perB;
  const int rem = bid % perB;
  const int tr = rem / tilesC, tc = rem % tilesC;
  const float* ib = in + (size_t)b * R * C;
  float* ob = out + (size_t)b * R * C;
  const int c = threadIdx.x & 63;
  const int r0 = threadIdx.x >> 6;
  #pragma unroll
  for (int i = 0; i < 16; ++i) {
    const int r = r0 + i * 4;
    t[r][c] = ib[(size_t)(tr * 64 + r) * C + tc * 64 + c];
  }
  __syncthreads();
  #pragma unroll
  for (int i = 0; i < 16; ++i) {
    const int r = r0 + i * 4;
    ob[(size_t)(tc * 64 + r) * R + tr * 64 + c] = t[c][r];
  }
}

// ---------------- FFT core ----------------
__device__ __forceinline__ void fft_stages(float2* bufA, float2* bufB,
                                           const float2* tw, int tid, float sign) {
  float2* src = bufA;
  float2* dst = bufB;
  int s = 1;
  for (int stage = 0; stage < 12; ++stage) {
    const int notm = ~(s - 1);
    #pragma unroll
    for (int i = 0; i < 8; ++i) {
      const int r = tid + (i << 8);
      const float2 a = src[r];
      const float2 b = src[r + 2048];
      const float2 w = tw[r & notm];
      const float wy = w.y * sign;
      const float dr = a.x - b.x;
      const float di = a.y - b.y;
      const int d0 = r + (r & notm);
      dst[d0] = make_float2(a.x + b.x, a.y + b.y);
      dst[d0 + s] = make_float2(dr * w.x - di * wy, dr * wy + di * w.x);
    }
    __syncthreads();
    float2* t = src; src = dst; dst = t;
    s <<= 1;
  }
}

__device__ __forceinline__ void mask_pair(float2* buf, const unsigned char* __restrict__ irb,
                                          int k, float ca, float sa, float cb, float sb) {
  const int m = (4096 - k) & 4095;
  const bool ik = irb[k] != 0;
  const bool im = irb[m] != 0;
  const float2 Zk = buf[k];
  const float2 Zm = buf[m];
  const float Ar = 0.5f * (Zk.x + Zm.x), Ai = 0.5f * (Zk.y - Zm.y);
  const float Br = 0.5f * (Zk.y + Zm.y), Bi = -0.5f * (Zk.x - Zm.x);
  const float Gar = 0.5f * ((ik ? ca : 1.0f) + (im ? ca : 1.0f));
  const float Gai = 0.5f * ((ik ? sa : 0.0f) - (im ? sa : 0.0f));
  const float Gbr = 0.5f * ((ik ? cb : 1.0f) + (im ? cb : 1.0f));
  const float Gbi = 0.5f * ((ik ? sb : 0.0f) - (im ? sb : 0.0f));
  const float har = Gar * Ar - Gai * Ai, hai = Gar * Ai + Gai * Ar;
  const float hbr = Gbr * Br - Gbi * Bi, hbi = Gbr * Bi + Gbi * Br;
  buf[k] = make_float2(har - hbi, hai + hbr);
  buf[m] = make_float2(har + hbi, hbr - hai);
}

// direct (fallback) variant: strided global access
__global__ __launch_bounds__(256) void k_fft_filter(const float* __restrict__ x,
                                                    const unsigned char* __restrict__ irr,
                                                    const float* __restrict__ sf,
                                                    float* __restrict__ out) {
  __shared__ float2 bufA[4096];
  __shared__ float2 bufB[4096];
  __shared__ float2 tw[2048];
  const int b = blockIdx.x >> 7;
  const int pr = blockIdx.x & 127;
  const int c0 = pr * 2;
  const int tid = threadIdx.x;
  for (int i = tid; i < 2048; i += 256) {
    float sn, cn;
    sincosf(-1.5339807878856412e-3f * (float)i, &sn, &cn);
    tw[i] = make_float2(cn, sn);
  }
  const float* xb = x + ((size_t)b * Tc) * Dc + c0;
  #pragma unroll
  for (int i = 0; i < 16; ++i) {
    const int t = tid + (i << 8);
    bufA[t] = *reinterpret_cast<const float2*>(xb + (size_t)t * Dc);
  }
  __syncthreads();
  fft_stages(bufA, bufB, tw, tid, 1.0f);
  float sa, ca, sb, cb;
  sincosf(sf[c0 & 3], &sa, &ca);
  sincosf(sf[(c0 + 1) & 3], &sb, &cb);
  const unsigned char* irb = irr + (size_t)b * Tc;
  #pragma unroll
  for (int i = 0; i < 8; ++i) mask_pair(bufA, irb, tid + (i << 8), ca, sa, cb, sb);
  if (tid == 0) mask_pair(bufA, irb, 2048, ca, sa, cb, sb);
  __syncthreads();
  fft_stages(bufA, bufB, tw, tid, -1.0f);
  float* ob = out + ((size_t)b * Tc) * Dc + c0;
  constexpr float invN = 1.0f / 4096.0f;
  #pragma unroll
  for (int i = 0; i < 16; ++i) {
    const int t = tid + (i << 8);
    const float2 y = bufA[t];
    *reinterpret_cast<float2*>(ob + (size_t)t * Dc) = make_float2(y.x * invN, y.y * invN);
  }
}

// transposed variant: coalesced rows of xT[b][d][t], filtered in place
__global__ __launch_bounds__(256) void k_fft_filterT(float* __restrict__ xT,
                                                     const unsigned char* __restrict__ irr,
                                                     const float* __restrict__ sf) {
  __shared__ float2 bufA[4096];
  __shared__ float2 bufB[4096];
  __shared__ float2 tw[2048];
  const int b = blockIdx.x >> 7;
  const int pr = blockIdx.x & 127;
  const int c0 = pr * 2;
  const int tid = threadIdx.x;
  for (int i = tid; i < 2048; i += 256) {
    float sn, cn;
    sincosf(-1.5339807878856412e-3f * (float)i, &sn, &cn);
    tw[i] = make_float2(cn, sn);
  }
  float* r0 = xT + (size_t)(b * Dc + c0) * Tc;
  float* r1 = r0 + Tc;
  #pragma unroll
  for (int i = 0; i < 4; ++i) {
    const int idx = tid + (i << 8);
    const float4 a0 = reinterpret_cast<const float4*>(r0)[idx];
    const float4 a1 = reinterpret_cast<const float4*>(r1)[idx];
    const int t4 = idx * 4;
    bufA[t4 + 0] = make_float2(a0.x, a1.x);
    bufA[t4 + 1] = make_float2(a0.y, a1.y);
    bufA[t4 + 2] = make_float2(a0.z, a1.z);
    bufA[t4 + 3] = make_float2(a0.w, a1.w);
  }
  __syncthreads();
  fft_stages(bufA, bufB, tw, tid, 1.0f);
  float sa, ca, sb, cb;
  sincosf(sf[c0 & 3], &sa, &ca);
  sincosf(sf[(c0 + 1) & 3], &sb, &cb);
  const unsigned char* irb = irr + (size_t)b * Tc;
  #pragma unroll
  for (int i = 0; i < 8; ++i) mask_pair(bufA, irb, tid + (i << 8), ca, sa, cb, sb);
  if (tid == 0) mask_pair(bufA, irb, 2048, ca, sa, cb, sb);
  __syncthreads();
  fft_stages(bufA, bufB, tw, tid, -1.0f);
  constexpr float invN = 1.0f / 4096.0f;
  #pragma unroll
  for (int i = 0; i < 4; ++i) {
    const int idx = tid + (i << 8);
    const int t4 = idx * 4;
    const float2 y0 = bufA[t4 + 0], y1 = bufA[t4 + 1];
    const float2 y2 = bufA[t4 + 2], y3 = bufA[t4 + 3];
    reinterpret_cast<float4*>(r0)[idx] =
        make_float4(y0.x * invN, y1.x * invN, y2.x * invN, y3.x * invN);
    reinterpret_cast<float4*>(r1)[idx] =
        make_float4(y0.y * invN, y1.y * invN, y2.y * invN, y3.y * invN);
  }
}

// ---------------- launch ----------------
extern "C" void kernel_launch(void* const* d_in, const int* in_sizes, int n_in,
                              void* d_out, int out_size, void* d_ws, size_t ws_size,
                              hipStream_t stream) {
  const float* x   = (const float*)d_in[0];
  const float* W1  = (const float*)d_in[1];
  const float* b1  = (const float*)d_in[2];
  const float* lng = (const float*)d_in[3];
  const float* lnb = (const float*)d_in[4];
  const float* W2  = (const float*)d_in[5];
  const float* b2  = (const float*)d_in[6];
  const float* tq  = (const float*)d_in[7];
  const float* sf  = (const float*)d_in[8];
  float* out = (float*)d_out;

  // Workspace layout — unconditional footprint kept at 704768 B (round-1 proven).
  // The split-weight buffers OVERLAY the scores region (scores dead after k_wsum;
  // k_prep is launched after k_wsum).
  char* ws = (char*)d_ws;
  float* scores        = (float*)(ws);                    // [0, 524288)
  unsigned short* w1h  = (unsigned short*)(ws);           // [0, 131072)  overlay
  unsigned short* w1l  = (unsigned short*)(ws + 131072);  // [131072, 262144)
  unsigned short* w2h  = (unsigned short*)(ws + 262144);  // [262144, 327680)
  unsigned short* w2l  = (unsigned short*)(ws + 327680);  // [327680, 393216)
  float* mt            = (float*)(ws + 524288);           // 32768
  float2* stats        = (float2*)(ws + 557056);          // 256
  float* tnorm         = (float*)(ws + 557312);           // 16384
  unsigned char* irr   = (unsigned char*)(ws + 573696);   // 131072 -> ends 704768
  float* xT            = (float*)(ws + 2097152);          // 134217728 (optional)
  const bool bigws = ws_size >= (size_t)2097152 + (size_t)134217728;

  hipMemsetAsync(mt, 0, Bc * Dc * sizeof(float), stream);

  k_scores<<<Bc * Tc / 32, 256, 0, stream>>>(x, tq, scores);
  k_smstats<<<Bc, 1024, 0, stream>>>(scores, stats);
  k_wsum<<<Bc * 16, 256, 0, stream>>>(x, scores, stats, mt);
  // scores dead from here; weight splits may overwrite it
  k_prep<<<96, 256, 0, stream>>>(W1, W2, w1h, w1l, w2h, w2l);
  k_tenc<<<Bc, 256, 0, stream>>>(mt, W1, b1, lng, lnb, W2, b2, tnorm);
  if (bigws) {
    k_transpose<<<Bc * 64 * 4, 256, 0, stream>>>(x, xT, Tc, Dc);
  }
  k_encode_mfma<<<Bc * Tc / 64, 256, 0, stream>>>(x, w1h, w1l, w2h, w2l,
                                                  b1, lng, lnb, b2, tnorm, irr);
  if (bigws) {
    k_fft_filterT<<<Bc * (Dc / 2), 256, 0, stream>>>(xT, irr, sf);
    k_transpose<<<Bc * 4 * 64, 256, 0, stream>>>(xT, out, Dc, Tc);
  } else {
    k_fft_filter<<<Bc * (Dc / 2), 256, 0, stream>>>(x, irr, sf, out);
  }
}